// Round 2
// baseline (623.342 us; speedup 1.0000x reference)
//
#include <hip/hip_runtime.h>
#include <hip/hip_bf16.h>

typedef __hip_bfloat16 bf16;
typedef __bf16 bf8v __attribute__((ext_vector_type(8)));
typedef float f4v __attribute__((ext_vector_type(4)));

// workspace layout (bytes)
#define WS_BIAS   0        // bf16[4][64][64]  = 32768
#define WS_TABLE  32768    // float[225][4]    = 3600 (padded to 4096)
#define WS_QKVT   36864    // bf16[384][128]   = 98304
#define WS_PROJT  135168   // bf16[128][128]   = 32768
#define WS_FLAG   167936   // int (1 = inputs are bf16, 0 = fp32)

__device__ __forceinline__ float rdf(const void* p, int i, int isbf) {
  return isbf ? __bfloat162float(((const bf16*)p)[i]) : ((const float*)p)[i];
}

__global__ void detect_dtype(const unsigned short* __restrict__ coords_raw,
                             char* __restrict__ ws) {
  // coords[0] == -1.0 exactly. fp32 -1.0 -> low half 0x0000; bf16 -1.0 -> 0xBF80.
  *(int*)(ws + WS_FLAG) = (coords_raw[0] != 0) ? 1 : 0;
}

__global__ void prep_transpose(const void* __restrict__ Wqkv,
                               const void* __restrict__ Wproj,
                               char* __restrict__ ws) {
  int idx = blockIdx.x * 256 + threadIdx.x;   // 65536 threads
  int isbf = *(const int*)(ws + WS_FLAG);
  bf16* qt = (bf16*)(ws + WS_QKVT);
  bf16* pt = (bf16*)(ws + WS_PROJT);
  if (idx < 384 * 128) {
    int c = idx >> 7, k = idx & 127;
    qt[idx] = __float2bfloat16(rdf(Wqkv, k * 384 + c, isbf));
  } else {
    int j = idx - 384 * 128;                  // < 16384
    int c = j >> 7, k = j & 127;
    pt[j] = __float2bfloat16(rdf(Wproj, k * 128 + c, isbf));
  }
}

__global__ void prep_table(const void* __restrict__ coords,
                           const void* __restrict__ w1,
                           const void* __restrict__ b1,
                           const void* __restrict__ w2,
                           const void* __restrict__ hts,
                           const void* __restrict__ pps,
                           const void* __restrict__ ws1,
                           const void* __restrict__ ws2,
                           char* __restrict__ ws) {
  int r = threadIdx.x;
  if (r >= 225) return;
  int isbf = *(const int*)(ws + WS_FLAG);
  float* table = (float*)(ws + WS_TABLE);
  float ht  = log1pf(__expf(rdf(hts, 0, isbf)));                 // softplus
  float pp  = 1.f / (1.f + __expf(-rdf(pps, 0, isbf)));          // sigmoid
  float wsv = log1pf(__expf(rdf(ws1, 0, isbf))) /
              log1pf(__expf(rdf(ws2, 0, isbf)));
  float t0 = rdf(coords, 2 * r + 0, isbf) * ht;
  float t1 = rdf(coords, 2 * r + 1, isbf) * ht;
  float s0 = (t0 > 0.f) ? 1.f : ((t0 < 0.f) ? -1.f : 0.f);
  float s1 = (t1 > 0.f) ? 1.f : ((t1 < 0.f) ? -1.f : 0.f);
  float u0 = s0 * __powf(fabsf(t0) + 1e-6f, pp) * wsv;
  float u1 = s1 * __powf(fabsf(t1) + 1e-6f, pp) * wsv;
  float a0 = 0.f, a1 = 0.f, a2 = 0.f, a3 = 0.f;
  for (int j = 0; j < 512; ++j) {
    float h = u0 * rdf(w1, j, isbf) + u1 * rdf(w1, 512 + j, isbf) + rdf(b1, j, isbf);
    h = fmaxf(h, 0.f);
    a0 += h * rdf(w2, 4 * j + 0, isbf);
    a1 += h * rdf(w2, 4 * j + 1, isbf);
    a2 += h * rdf(w2, 4 * j + 2, isbf);
    a3 += h * rdf(w2, 4 * j + 3, isbf);
  }
  table[4 * r + 0] = a0; table[4 * r + 1] = a1;
  table[4 * r + 2] = a2; table[4 * r + 3] = a3;
}

__global__ void prep_gather(const int* __restrict__ rel, char* __restrict__ ws) {
  int pos = blockIdx.x * 256 + threadIdx.x;   // 4096 positions (i*64+j)
  const float* table = (const float*)(ws + WS_TABLE);
  bf16* bias = (bf16*)(ws + WS_BIAS);
  int r = rel[pos];
#pragma unroll
  for (int h = 0; h < 4; ++h)
    bias[h * 4096 + pos] = __float2bfloat16(table[r * 4 + h]);
}

// One block per window; wave w == head h. LDS:
//   [0, 17408)      os : attn-out staging [64][136] bf16
//   [17408, 54272)  per-wave scratch 9216 B each (vT -> q -> k -> P); later
//                   reused (after barrier #1) as fsf[64][128] float staging.
__global__ __launch_bounds__(256, 3) void wattn_main(
    const void* __restrict__ xp,
    const char* __restrict__ ws,
    const void* __restrict__ bprojp,
    void* __restrict__ outp) {
  __shared__ alignas(16) char smem[54272];
  bf16* os = (bf16*)smem;                                   // [64][136]
  const int tid  = threadIdx.x;
  const int w    = tid >> 6;
  const int lane = tid & 63;
  const int l16  = lane & 15;
  const int quad = lane >> 4;
  bf16* scr = (bf16*)(smem + 17408 + w * 9216);             // 4608 bf16 elems

  const int isbf = *(const int*)(ws + WS_FLAG);
  const bf16* WqkvT  = (const bf16*)(ws + WS_QKVT);
  const bf16* WprojT = (const bf16*)(ws + WS_PROJT);
  const bf16* biasg  = (const bf16*)(ws + WS_BIAS);

  const int b = blockIdx.x;

  // x A-fragments (shared across q/k/v), straight from global (L2-hot)
  bf8v xa[4][4];
  if (isbf) {
    const bf16* xb = (const bf16*)xp + (size_t)b * 8192;
#pragma unroll
    for (int mt = 0; mt < 4; ++mt)
#pragma unroll
      for (int ks = 0; ks < 4; ++ks)
        xa[mt][ks] = *(const bf8v*)(xb + (mt * 16 + l16) * 128 + ks * 32 + quad * 8);
  } else {
    const float* xb = (const float*)xp + (size_t)b * 8192;
#pragma unroll
    for (int mt = 0; mt < 4; ++mt)
#pragma unroll
      for (int ks = 0; ks < 4; ++ks) {
        const float* src = xb + (mt * 16 + l16) * 128 + ks * 32 + quad * 8;
        f4v a = *(const f4v*)(src);
        f4v c = *(const f4v*)(src + 4);
        union { bf8v v; bf16 h[8]; } u;
#pragma unroll
        for (int j = 0; j < 4; ++j) {
          u.h[j]     = __float2bfloat16(a[j]);
          u.h[4 + j] = __float2bfloat16(c[j]);
        }
        xa[mt][ks] = u.v;
      }
  }

  const f4v zf = {0.f, 0.f, 0.f, 0.f};
  bf8v vf[2][2], qf[4], kf[4];

  // ---- stage V (cols 256 + w*32) : write transposed vT[32][72], load B-frags ----
  {
    f4v acc[4][2];
#pragma unroll
    for (int mt = 0; mt < 4; ++mt) { acc[mt][0] = zf; acc[mt][1] = zf; }
    const bf16* Bb = WqkvT + (size_t)(256 + w * 32) * 128;
#pragma unroll
    for (int ks = 0; ks < 4; ++ks)
#pragma unroll
      for (int nt = 0; nt < 2; ++nt) {
        bf8v bfr = *(const bf8v*)(Bb + (nt * 16 + l16) * 128 + ks * 32 + quad * 8);
#pragma unroll
        for (int mt = 0; mt < 4; ++mt)
          acc[mt][nt] = __builtin_amdgcn_mfma_f32_16x16x32_bf16(xa[mt][ks], bfr, acc[mt][nt], 0, 0, 0);
      }
#pragma unroll
    for (int mt = 0; mt < 4; ++mt)
#pragma unroll
      for (int nt = 0; nt < 2; ++nt)
#pragma unroll
        for (int r = 0; r < 4; ++r)
          scr[(nt * 16 + l16) * 72 + mt * 16 + quad * 4 + r] = __float2bfloat16(acc[mt][nt][r]);
#pragma unroll
    for (int k2 = 0; k2 < 2; ++k2)
#pragma unroll
      for (int nt = 0; nt < 2; ++nt)
        vf[k2][nt] = *(const bf8v*)(scr + (nt * 16 + l16) * 72 + k2 * 32 + quad * 8);
  }

  // ---- stage Q (cols 0 + w*32) : token-major [64][40], load A-frags ----
  {
    f4v acc[4][2];
#pragma unroll
    for (int mt = 0; mt < 4; ++mt) { acc[mt][0] = zf; acc[mt][1] = zf; }
    const bf16* Bb = WqkvT + (size_t)(w * 32) * 128;
#pragma unroll
    for (int ks = 0; ks < 4; ++ks)
#pragma unroll
      for (int nt = 0; nt < 2; ++nt) {
        bf8v bfr = *(const bf8v*)(Bb + (nt * 16 + l16) * 128 + ks * 32 + quad * 8);
#pragma unroll
        for (int mt = 0; mt < 4; ++mt)
          acc[mt][nt] = __builtin_amdgcn_mfma_f32_16x16x32_bf16(xa[mt][ks], bfr, acc[mt][nt], 0, 0, 0);
      }
#pragma unroll
    for (int mt = 0; mt < 4; ++mt)
#pragma unroll
      for (int nt = 0; nt < 2; ++nt)
#pragma unroll
        for (int r = 0; r < 4; ++r)
          scr[(mt * 16 + quad * 4 + r) * 40 + nt * 16 + l16] = __float2bfloat16(acc[mt][nt][r]);
#pragma unroll
    for (int mt = 0; mt < 4; ++mt)
      qf[mt] = *(const bf8v*)(scr + (mt * 16 + l16) * 40 + quad * 8);
  }

  // ---- stage K (cols 128 + w*32) ----
  {
    f4v acc[4][2];
#pragma unroll
    for (int mt = 0; mt < 4; ++mt) { acc[mt][0] = zf; acc[mt][1] = zf; }
    const bf16* Bb = WqkvT + (size_t)(128 + w * 32) * 128;
#pragma unroll
    for (int ks = 0; ks < 4; ++ks)
#pragma unroll
      for (int nt = 0; nt < 2; ++nt) {
        bf8v bfr = *(const bf8v*)(Bb + (nt * 16 + l16) * 128 + ks * 32 + quad * 8);
#pragma unroll
        for (int mt = 0; mt < 4; ++mt)
          acc[mt][nt] = __builtin_amdgcn_mfma_f32_16x16x32_bf16(xa[mt][ks], bfr, acc[mt][nt], 0, 0, 0);
      }
#pragma unroll
    for (int mt = 0; mt < 4; ++mt)
#pragma unroll
      for (int nt = 0; nt < 2; ++nt)
#pragma unroll
        for (int r = 0; r < 4; ++r)
          scr[(mt * 16 + quad * 4 + r) * 40 + nt * 16 + l16] = __float2bfloat16(acc[mt][nt][r]);
#pragma unroll
    for (int n4 = 0; n4 < 4; ++n4)
      kf[n4] = *(const bf8v*)(scr + (n4 * 16 + l16) * 40 + quad * 8);
  }

  // ---- attention: scores -> +bias -> softmax (quad shuffles) -> P@v ----
  const float scale = 0.1767766952966369f;   // 32^-0.5
  const bf16* bh = biasg + w * 4096;
  for (int mt = 0; mt < 4; ++mt) {
    f4v sc[4];
#pragma unroll
    for (int n4 = 0; n4 < 4; ++n4)
      sc[n4] = __builtin_amdgcn_mfma_f32_16x16x32_bf16(qf[mt], kf[n4], zf, 0, 0, 0);
    float p[4][4];
#pragma unroll
    for (int n4 = 0; n4 < 4; ++n4)
#pragma unroll
      for (int r = 0; r < 4; ++r) {
        int i = mt * 16 + quad * 4 + r;
        int j = n4 * 16 + l16;
        p[n4][r] = sc[n4][r] * scale + __bfloat162float(bh[i * 64 + j]);
      }
#pragma unroll
    for (int r = 0; r < 4; ++r) {
      float m = fmaxf(fmaxf(p[0][r], p[1][r]), fmaxf(p[2][r], p[3][r]));
      m = fmaxf(m, __shfl_xor(m, 1, 16));
      m = fmaxf(m, __shfl_xor(m, 2, 16));
      m = fmaxf(m, __shfl_xor(m, 4, 16));
      m = fmaxf(m, __shfl_xor(m, 8, 16));
      float s = 0.f;
#pragma unroll
      for (int n4 = 0; n4 < 4; ++n4) { p[n4][r] = __expf(p[n4][r] - m); s += p[n4][r]; }
      s += __shfl_xor(s, 1, 16);
      s += __shfl_xor(s, 2, 16);
      s += __shfl_xor(s, 4, 16);
      s += __shfl_xor(s, 8, 16);
      float inv = __builtin_amdgcn_rcpf(s);
#pragma unroll
      for (int n4 = 0; n4 < 4; ++n4) p[n4][r] *= inv;
    }
#pragma unroll
    for (int n4 = 0; n4 < 4; ++n4)
#pragma unroll
      for (int r = 0; r < 4; ++r)
        scr[(mt * 16 + quad * 4 + r) * 72 + n4 * 16 + l16] = __float2bfloat16(p[n4][r]);

    f4v o2[2] = {zf, zf};
#pragma unroll
    for (int k2 = 0; k2 < 2; ++k2) {
      bf8v pf = *(const bf8v*)(scr + (mt * 16 + l16) * 72 + k2 * 32 + quad * 8);
#pragma unroll
      for (int nt = 0; nt < 2; ++nt)
        o2[nt] = __builtin_amdgcn_mfma_f32_16x16x32_bf16(pf, vf[k2][nt], o2[nt], 0, 0, 0);
    }
#pragma unroll
    for (int nt = 0; nt < 2; ++nt)
#pragma unroll
      for (int r = 0; r < 4; ++r)
        os[(mt * 16 + quad * 4 + r) * 136 + w * 32 + nt * 16 + l16] = __float2bfloat16(o2[nt][r]);
  }

  __syncthreads();   // os fully written; per-wave scratch dead from here on

  // ---- proj: out = os @ W_proj + b_proj ; wave w covers cols [w*32, w*32+32) ----
  f4v pa[4][2];
#pragma unroll
  for (int mt = 0; mt < 4; ++mt) { pa[mt][0] = zf; pa[mt][1] = zf; }
#pragma unroll
  for (int ks = 0; ks < 4; ++ks) {
    bf8v oa[4];
#pragma unroll
    for (int mt = 0; mt < 4; ++mt)
      oa[mt] = *(const bf8v*)(os + (mt * 16 + l16) * 136 + ks * 32 + quad * 8);
#pragma unroll
    for (int nt = 0; nt < 2; ++nt) {
      bf8v bfr = *(const bf8v*)(WprojT + (size_t)(w * 32 + nt * 16 + l16) * 128 + ks * 32 + quad * 8);
#pragma unroll
      for (int mt = 0; mt < 4; ++mt)
        pa[mt][nt] = __builtin_amdgcn_mfma_f32_16x16x32_bf16(oa[mt], bfr, pa[mt][nt], 0, 0, 0);
    }
  }

  // epilogue into fp32 staging (aliases dead per-wave scratch), then coalesced copy
  float* fsf = (float*)(smem + 17408);                      // [64][128] fp32 = 32 KB
#pragma unroll
  for (int nt = 0; nt < 2; ++nt) {
    int c = w * 32 + nt * 16 + l16;
    float bb = rdf(bprojp, c, isbf);
#pragma unroll
    for (int mt = 0; mt < 4; ++mt)
#pragma unroll
      for (int r = 0; r < 4; ++r)
        fsf[(mt * 16 + quad * 4 + r) * 128 + c] = pa[mt][nt][r] + bb;
  }
  __syncthreads();

  if (isbf) {
    bf16* ob = (bf16*)outp + (size_t)b * 8192;
#pragma unroll
    for (int it = 0; it < 4; ++it) {
      int e = (tid + it * 256) * 8;
      f4v a = *(const f4v*)(fsf + e);
      f4v c = *(const f4v*)(fsf + e + 4);
      union { uint4 u; bf16 h[8]; } pk;
#pragma unroll
      for (int j = 0; j < 4; ++j) {
        pk.h[j]     = __float2bfloat16(a[j]);
        pk.h[4 + j] = __float2bfloat16(c[j]);
      }
      *(uint4*)(ob + e) = pk.u;
    }
  } else {
    float* ob = (float*)outp + (size_t)b * 8192;
#pragma unroll
    for (int it = 0; it < 8; ++it) {
      int e = (tid + it * 256) * 4;
      *(f4v*)(ob + e) = *(const f4v*)(fsf + e);
    }
  }
}

extern "C" void kernel_launch(void* const* d_in, const int* in_sizes, int n_in,
                              void* d_out, int out_size, void* d_ws, size_t ws_size,
                              hipStream_t stream) {
  const void* x      = d_in[0];
  const void* Wqkv   = d_in[1];
  const void* Wproj  = d_in[2];
  const void* bproj  = d_in[3];
  const void* w1     = d_in[4];
  const void* b1     = d_in[5];
  const void* w2     = d_in[6];
  const void* hts    = d_in[7];
  const void* pps    = d_in[8];
  const void* ws1    = d_in[9];
  const void* ws2    = d_in[10];
  const int*  rel    = (const int*)d_in[11];
  const void* coords = d_in[12];
  char* ws  = (char*)d_ws;

  detect_dtype<<<1, 1, 0, stream>>>((const unsigned short*)coords, ws);
  prep_transpose<<<256, 256, 0, stream>>>(Wqkv, Wproj, ws);
  prep_table<<<1, 256, 0, stream>>>(coords, w1, b1, w2, hts, pps, ws1, ws2, ws);
  prep_gather<<<16, 256, 0, stream>>>(rel, ws);
  wattn_main<<<4096, 256, 0, stream>>>(x, ws, bproj, d_out);
}

// Round 3
// 346.315 us; speedup vs baseline: 1.7999x; 1.7999x over previous
//
#include <hip/hip_runtime.h>
#include <hip/hip_bf16.h>

typedef __hip_bfloat16 bf16;
typedef __bf16 bf8v __attribute__((ext_vector_type(8)));
typedef float f4v __attribute__((ext_vector_type(4)));

// workspace layout (bytes)
#define WS_BIAS   0        // bf16, MFMA-C-layout-permuted [4][4][4][4][16][4] = 32768
#define WS_TABLE  32768    // float[225][4]    = 3600 (padded to 4096)
#define WS_QKVT   36864    // bf16[384][128]   = 98304
#define WS_PROJT  135168   // bf16[128][128]   = 32768
#define WS_FLAG   167936   // int (1 = inputs are bf16, 0 = fp32)

__device__ __forceinline__ float rdf(const void* p, int i, int isbf) {
  return isbf ? __bfloat162float(((const bf16*)p)[i]) : ((const float*)p)[i];
}

__global__ void detect_dtype(const unsigned short* __restrict__ coords_raw,
                             char* __restrict__ ws) {
  // coords[0] == -1.0 exactly. fp32 -1.0 -> low half 0x0000; bf16 -1.0 -> 0xBF80.
  *(int*)(ws + WS_FLAG) = (coords_raw[0] != 0) ? 1 : 0;
}

__global__ void prep_transpose(const void* __restrict__ Wqkv,
                               const void* __restrict__ Wproj,
                               char* __restrict__ ws) {
  int idx = blockIdx.x * 256 + threadIdx.x;   // 65536 threads
  int isbf = *(const int*)(ws + WS_FLAG);
  bf16* qt = (bf16*)(ws + WS_QKVT);
  bf16* pt = (bf16*)(ws + WS_PROJT);
  if (idx < 384 * 128) {
    int c = idx >> 7, k = idx & 127;
    qt[idx] = __float2bfloat16(rdf(Wqkv, k * 384 + c, isbf));
  } else {
    int j = idx - 384 * 128;                  // < 16384
    int c = j >> 7, k = j & 127;
    pt[j] = __float2bfloat16(rdf(Wproj, k * 128 + c, isbf));
  }
}

// 225 blocks x 512 threads: one hidden unit per thread, reduce across block.
__global__ void prep_table(const void* __restrict__ coords,
                           const void* __restrict__ w1,
                           const void* __restrict__ b1,
                           const void* __restrict__ w2,
                           const void* __restrict__ hts,
                           const void* __restrict__ pps,
                           const void* __restrict__ ws1,
                           const void* __restrict__ ws2,
                           char* __restrict__ ws) {
  __shared__ float red[8][4];
  const int r = blockIdx.x;       // 0..224
  const int j = threadIdx.x;      // 0..511
  const int isbf = *(const int*)(ws + WS_FLAG);
  float* table = (float*)(ws + WS_TABLE);

  float ht  = log1pf(__expf(rdf(hts, 0, isbf)));                 // softplus
  float pp  = 1.f / (1.f + __expf(-rdf(pps, 0, isbf)));          // sigmoid
  float wsv = log1pf(__expf(rdf(ws1, 0, isbf))) /
              log1pf(__expf(rdf(ws2, 0, isbf)));
  float t0 = rdf(coords, 2 * r + 0, isbf) * ht;
  float t1 = rdf(coords, 2 * r + 1, isbf) * ht;
  float s0 = (t0 > 0.f) ? 1.f : ((t0 < 0.f) ? -1.f : 0.f);
  float s1 = (t1 > 0.f) ? 1.f : ((t1 < 0.f) ? -1.f : 0.f);
  float u0 = s0 * __powf(fabsf(t0) + 1e-6f, pp) * wsv;
  float u1 = s1 * __powf(fabsf(t1) + 1e-6f, pp) * wsv;

  float h = u0 * rdf(w1, j, isbf) + u1 * rdf(w1, 512 + j, isbf) + rdf(b1, j, isbf);
  h = fmaxf(h, 0.f);
  float a[4];
#pragma unroll
  for (int q = 0; q < 4; ++q) a[q] = h * rdf(w2, 4 * j + q, isbf);
#pragma unroll
  for (int off = 1; off < 64; off <<= 1)
#pragma unroll
    for (int q = 0; q < 4; ++q) a[q] += __shfl_xor(a[q], off);
  int wv = j >> 6, ln = j & 63;
  if (ln == 0) {
#pragma unroll
    for (int q = 0; q < 4; ++q) red[wv][q] = a[q];
  }
  __syncthreads();
  if (j < 4) {
    float s = 0.f;
#pragma unroll
    for (int w8 = 0; w8 < 8; ++w8) s += red[w8][j];
    table[r * 4 + j] = s;
  }
}

// Permute bias into exact MFMA C-layout order:
//   elem = h*4096 + mt*1024 + n4*256 + quad*64 + l16*4 + r
// so wattn_main reads one uint2 (4 bf16, r=0..3) per (mt, n4).
__global__ void prep_gather(const int* __restrict__ rel, char* __restrict__ ws) {
  int pos = blockIdx.x * 256 + threadIdx.x;   // 4096
  const float* table = (const float*)(ws + WS_TABLE);
  bf16* bias = (bf16*)(ws + WS_BIAS);
  int h = pos >> 10, rest = pos & 1023;
  int mt = rest >> 8, n4 = (rest >> 6) & 3, quad = (rest >> 4) & 3, l16 = rest & 15;
  int jj = n4 * 16 + l16;
  union { uint2 u; bf16 hh[4]; } pk;
#pragma unroll
  for (int r = 0; r < 4; ++r) {
    int i = mt * 16 + quad * 4 + r;
    int rr = rel[i * 64 + jj];
    pk.hh[r] = __float2bfloat16(table[rr * 4 + h]);
  }
  *(uint2*)(bias + pos * 4) = pk.u;
}

// One block per window; wave w == head h. LDS:
//   [0, 17408)      xls : x staged as bf16 [64][136]  -> later reused as os [64][136]
//   [17408, 54272)  per-wave scratch 9216 B each (vT -> q -> k -> P); later
//                   reused (after proj barrier) as fsf[64][128] float staging.
__global__ __launch_bounds__(256, 3) void wattn_main(
    const void* __restrict__ xp,
    const char* __restrict__ ws,
    const void* __restrict__ bprojp,
    void* __restrict__ outp) {
  __shared__ alignas(16) char smem[54272];
  bf16* xls = (bf16*)smem;                                  // [64][136]
  bf16* os  = (bf16*)smem;                                  // [64][136] (after stages)
  const int tid  = threadIdx.x;
  const int w    = tid >> 6;
  const int lane = tid & 63;
  const int l16  = lane & 15;
  const int quad = lane >> 4;
  bf16* scr = (bf16*)(smem + 17408 + w * 9216);             // 4608 bf16 elems

  const int isbf = *(const int*)(ws + WS_FLAG);
  const bf16* WqkvT  = (const bf16*)(ws + WS_QKVT);
  const bf16* WprojT = (const bf16*)(ws + WS_PROJT);
  const bf16* biasg  = (const bf16*)(ws + WS_BIAS);

  const int b = blockIdx.x;

  // ---- stage x -> LDS (bf16, padded rows: stride 136 elems = 272 B) ----
  if (isbf) {
    const bf16* xb = (const bf16*)xp + (size_t)b * 8192;
#pragma unroll
    for (int it = 0; it < 4; ++it) {
      int e = (tid + it * 256) * 8;
      int row = e >> 7, col = e & 127;
      *(uint4*)(xls + row * 136 + col) = *(const uint4*)(xb + e);
    }
  } else {
    const float* xb = (const float*)xp + (size_t)b * 8192;
#pragma unroll
    for (int it = 0; it < 4; ++it) {
      int e = (tid + it * 256) * 8;
      int row = e >> 7, col = e & 127;
      f4v a = *(const f4v*)(xb + e);
      f4v c = *(const f4v*)(xb + e + 4);
      union { uint4 u; bf16 h[8]; } pk;
#pragma unroll
      for (int jj = 0; jj < 4; ++jj) {
        pk.h[jj]     = __float2bfloat16(a[jj]);
        pk.h[4 + jj] = __float2bfloat16(c[jj]);
      }
      *(uint4*)(xls + row * 136 + col) = pk.u;
    }
  }
  __syncthreads();

  const f4v zf = {0.f, 0.f, 0.f, 0.f};
  bf8v vf[2][2], qf[4], kf[4];

  auto run_qkv = [&](int colbase, f4v (&acc)[4][2]) {
    const bf16* Bb = WqkvT + (size_t)colbase * 128;
#pragma unroll
    for (int ks = 0; ks < 4; ++ks) {
      bf8v xk[4];
#pragma unroll
      for (int mt = 0; mt < 4; ++mt)
        xk[mt] = *(const bf8v*)(xls + (mt * 16 + l16) * 136 + ks * 32 + quad * 8);
#pragma unroll
      for (int nt = 0; nt < 2; ++nt) {
        bf8v bfr = *(const bf8v*)(Bb + (nt * 16 + l16) * 128 + ks * 32 + quad * 8);
#pragma unroll
        for (int mt = 0; mt < 4; ++mt)
          acc[mt][nt] = __builtin_amdgcn_mfma_f32_16x16x32_bf16(xk[mt], bfr, acc[mt][nt], 0, 0, 0);
      }
    }
  };

  // ---- stage V (cols 256 + w*32): write transposed vT[32][72] (packed b64) ----
  {
    f4v acc[4][2];
#pragma unroll
    for (int mt = 0; mt < 4; ++mt) { acc[mt][0] = zf; acc[mt][1] = zf; }
    run_qkv(256 + w * 32, acc);
#pragma unroll
    for (int mt = 0; mt < 4; ++mt)
#pragma unroll
      for (int nt = 0; nt < 2; ++nt) {
        union { uint2 u; bf16 h[4]; } pk;
#pragma unroll
        for (int r = 0; r < 4; ++r) pk.h[r] = __float2bfloat16(acc[mt][nt][r]);
        *(uint2*)(scr + (nt * 16 + l16) * 72 + mt * 16 + quad * 4) = pk.u;
      }
#pragma unroll
    for (int k2 = 0; k2 < 2; ++k2)
#pragma unroll
      for (int nt = 0; nt < 2; ++nt)
        vf[k2][nt] = *(const bf8v*)(scr + (nt * 16 + l16) * 72 + k2 * 32 + quad * 8);
  }

  // ---- stage Q (cols 0 + w*32): token-major [64][40], load A-frags ----
  {
    f4v acc[4][2];
#pragma unroll
    for (int mt = 0; mt < 4; ++mt) { acc[mt][0] = zf; acc[mt][1] = zf; }
    run_qkv(w * 32, acc);
#pragma unroll
    for (int mt = 0; mt < 4; ++mt)
#pragma unroll
      for (int nt = 0; nt < 2; ++nt)
#pragma unroll
        for (int r = 0; r < 4; ++r)
          scr[(mt * 16 + quad * 4 + r) * 40 + nt * 16 + l16] = __float2bfloat16(acc[mt][nt][r]);
#pragma unroll
    for (int mt = 0; mt < 4; ++mt)
      qf[mt] = *(const bf8v*)(scr + (mt * 16 + l16) * 40 + quad * 8);
  }

  // ---- stage K (cols 128 + w*32) ----
  {
    f4v acc[4][2];
#pragma unroll
    for (int mt = 0; mt < 4; ++mt) { acc[mt][0] = zf; acc[mt][1] = zf; }
    run_qkv(128 + w * 32, acc);
#pragma unroll
    for (int mt = 0; mt < 4; ++mt)
#pragma unroll
      for (int nt = 0; nt < 2; ++nt)
#pragma unroll
        for (int r = 0; r < 4; ++r)
          scr[(mt * 16 + quad * 4 + r) * 40 + nt * 16 + l16] = __float2bfloat16(acc[mt][nt][r]);
#pragma unroll
    for (int n4 = 0; n4 < 4; ++n4)
      kf[n4] = *(const bf8v*)(scr + (n4 * 16 + l16) * 40 + quad * 8);
  }

  __syncthreads();   // all waves done reading xls; os (same region) now writable

  // ---- attention: scores -> +bias -> softmax (quad shuffles) -> P@v ----
  const float scale = 0.1767766952966369f;   // 32^-0.5
  const bf16* bh = biasg + w * 4096;
  for (int mt = 0; mt < 4; ++mt) {
    f4v sc[4];
#pragma unroll
    for (int n4 = 0; n4 < 4; ++n4)
      sc[n4] = __builtin_amdgcn_mfma_f32_16x16x32_bf16(qf[mt], kf[n4], zf, 0, 0, 0);
    float p[4][4];
#pragma unroll
    for (int n4 = 0; n4 < 4; ++n4) {
      union { uint2 u; bf16 hh[4]; } bb;
      bb.u = *(const uint2*)(bh + mt * 1024 + n4 * 256 + quad * 64 + l16 * 4);
#pragma unroll
      for (int r = 0; r < 4; ++r)
        p[n4][r] = sc[n4][r] * scale + __bfloat162float(bb.hh[r]);
    }
#pragma unroll
    for (int r = 0; r < 4; ++r) {
      float m = fmaxf(fmaxf(p[0][r], p[1][r]), fmaxf(p[2][r], p[3][r]));
      m = fmaxf(m, __shfl_xor(m, 1, 16));
      m = fmaxf(m, __shfl_xor(m, 2, 16));
      m = fmaxf(m, __shfl_xor(m, 4, 16));
      m = fmaxf(m, __shfl_xor(m, 8, 16));
      float s = 0.f;
#pragma unroll
      for (int n4 = 0; n4 < 4; ++n4) { p[n4][r] = __expf(p[n4][r] - m); s += p[n4][r]; }
      s += __shfl_xor(s, 1, 16);
      s += __shfl_xor(s, 2, 16);
      s += __shfl_xor(s, 4, 16);
      s += __shfl_xor(s, 8, 16);
      float inv = __builtin_amdgcn_rcpf(s);
#pragma unroll
      for (int n4 = 0; n4 < 4; ++n4) p[n4][r] *= inv;
    }
#pragma unroll
    for (int n4 = 0; n4 < 4; ++n4)
#pragma unroll
      for (int r = 0; r < 4; ++r)
        scr[(mt * 16 + quad * 4 + r) * 72 + n4 * 16 + l16] = __float2bfloat16(p[n4][r]);

    f4v o2[2] = {zf, zf};
#pragma unroll
    for (int k2 = 0; k2 < 2; ++k2) {
      bf8v pf = *(const bf8v*)(scr + (mt * 16 + l16) * 72 + k2 * 32 + quad * 8);
#pragma unroll
      for (int nt = 0; nt < 2; ++nt)
        o2[nt] = __builtin_amdgcn_mfma_f32_16x16x32_bf16(pf, vf[k2][nt], o2[nt], 0, 0, 0);
    }
#pragma unroll
    for (int nt = 0; nt < 2; ++nt) {
      union { uint2 u; bf16 h[4]; } pk;
#pragma unroll
      for (int r = 0; r < 4; ++r) pk.h[r] = __float2bfloat16(o2[nt][r]);
      // os row = mt*16+quad*4+r, col = w*32+nt*16+l16 -> r not contiguous; scalar
#pragma unroll
      for (int r = 0; r < 4; ++r)
        os[(mt * 16 + quad * 4 + r) * 136 + w * 32 + nt * 16 + l16] = pk.h[r];
    }
  }

  __syncthreads();   // os fully written; per-wave scratch dead from here on

  // ---- proj: out = os @ W_proj + b_proj ; wave w covers cols [w*32, w*32+32) ----
  f4v pa[4][2];
#pragma unroll
  for (int mt = 0; mt < 4; ++mt) { pa[mt][0] = zf; pa[mt][1] = zf; }
#pragma unroll
  for (int ks = 0; ks < 4; ++ks) {
    bf8v oa[4];
#pragma unroll
    for (int mt = 0; mt < 4; ++mt)
      oa[mt] = *(const bf8v*)(os + (mt * 16 + l16) * 136 + ks * 32 + quad * 8);
#pragma unroll
    for (int nt = 0; nt < 2; ++nt) {
      bf8v bfr = *(const bf8v*)(WprojT + (size_t)(w * 32 + nt * 16 + l16) * 128 + ks * 32 + quad * 8);
#pragma unroll
      for (int mt = 0; mt < 4; ++mt)
        pa[mt][nt] = __builtin_amdgcn_mfma_f32_16x16x32_bf16(oa[mt], bfr, pa[mt][nt], 0, 0, 0);
    }
  }

  // epilogue into fp32 staging (aliases dead per-wave scratch), then coalesced copy
  float* fsf = (float*)(smem + 17408);                      // [64][128] fp32 = 32 KB
#pragma unroll
  for (int nt = 0; nt < 2; ++nt) {
    int c = w * 32 + nt * 16 + l16;
    float bb = rdf(bprojp, c, isbf);
#pragma unroll
    for (int mt = 0; mt < 4; ++mt)
#pragma unroll
      for (int r = 0; r < 4; ++r)
        fsf[(mt * 16 + quad * 4 + r) * 128 + c] = pa[mt][nt][r] + bb;
  }
  __syncthreads();

  if (isbf) {
    bf16* ob = (bf16*)outp + (size_t)b * 8192;
#pragma unroll
    for (int it = 0; it < 4; ++it) {
      int e = (tid + it * 256) * 8;
      f4v a = *(const f4v*)(fsf + e);
      f4v c = *(const f4v*)(fsf + e + 4);
      union { uint4 u; bf16 h[8]; } pk;
#pragma unroll
      for (int jj = 0; jj < 4; ++jj) {
        pk.h[jj]     = __float2bfloat16(a[jj]);
        pk.h[4 + jj] = __float2bfloat16(c[jj]);
      }
      *(uint4*)(ob + e) = pk.u;
    }
  } else {
    float* ob = (float*)outp + (size_t)b * 8192;
#pragma unroll
    for (int it = 0; it < 8; ++it) {
      int e = (tid + it * 256) * 4;
      *(f4v*)(ob + e) = *(const f4v*)(fsf + e);
    }
  }
}

extern "C" void kernel_launch(void* const* d_in, const int* in_sizes, int n_in,
                              void* d_out, int out_size, void* d_ws, size_t ws_size,
                              hipStream_t stream) {
  const void* x      = d_in[0];
  const void* Wqkv   = d_in[1];
  const void* Wproj  = d_in[2];
  const void* bproj  = d_in[3];
  const void* w1     = d_in[4];
  const void* b1     = d_in[5];
  const void* w2     = d_in[6];
  const void* hts    = d_in[7];
  const void* pps    = d_in[8];
  const void* ws1    = d_in[9];
  const void* ws2    = d_in[10];
  const int*  rel    = (const int*)d_in[11];
  const void* coords = d_in[12];
  char* ws  = (char*)d_ws;

  detect_dtype<<<1, 1, 0, stream>>>((const unsigned short*)coords, ws);
  prep_transpose<<<256, 256, 0, stream>>>(Wqkv, Wproj, ws);
  prep_table<<<225, 512, 0, stream>>>(coords, w1, b1, w2, hts, pps, ws1, ws2, ws);
  prep_gather<<<16, 256, 0, stream>>>(rel, ws);
  wattn_main<<<4096, 256, 0, stream>>>(x, ws, bproj, d_out);
}